// Round 5
// baseline (289.800 us; speedup 1.0000x reference)
//
#include <hip/hip_runtime.h>
#include <hip/hip_bf16.h>
#include <math.h>

#define TPB 256

typedef __attribute__((ext_vector_type(8))) short bf16x8;
typedef __attribute__((ext_vector_type(4))) float f32x4;

__device__ __forceinline__ short f2bs(float x) {
  __hip_bfloat16 h = __float2bfloat16(x);
  return *reinterpret_cast<short*>(&h);
}

__device__ __forceinline__ void gll16(const void* g, void* l) {
  __builtin_amdgcn_global_load_lds(
      (const __attribute__((address_space(1))) unsigned int*)g,
      (__attribute__((address_space(3))) unsigned int*)l, 16, 0, 0);
}

// ---------------------------------------------------------------------------
// fp32 -> bf16 flat convert
// ---------------------------------------------------------------------------
__global__ __launch_bounds__(TPB) void cvt_f2b(
    const float* __restrict__ s, short* __restrict__ d, int n)
{
  int i = (blockIdx.x * TPB + threadIdx.x) << 2;
  if (i >= n) return;
  const float4 v = *(const float4*)(s + i);
  short4 o;
  o.x = f2bs(v.x); o.y = f2bs(v.y); o.z = f2bs(v.z); o.w = f2bs(v.w);
  *(short4*)(d + i) = o;
}

// ---------------------------------------------------------------------------
// All weight tensors -> bf16 in one launch. 1024-elem blocks per segment:
// Wq_nope 2048 | Wq_rope 2048 | W_kv_down 1024 | W_k_nope 128 | W_k_rope 128
// | W_v 256 | W_o 4096   => 9728 blocks
// ---------------------------------------------------------------------------
__global__ __launch_bounds__(TPB) void cvt_weights(
    const float* __restrict__ w0, const float* __restrict__ w1,
    const float* __restrict__ w2, const float* __restrict__ w3,
    const float* __restrict__ w4, const float* __restrict__ w5,
    const float* __restrict__ w6,
    short* __restrict__ Wcat, short* __restrict__ Wkvb, short* __restrict__ Wob)
{
  int b = blockIdx.x;
  const float* src; short* dst; int base;
  if (b < 2048)      { src = w0; dst = Wcat;           base = b; }
  else if (b < 4096) { src = w1; dst = Wcat + 2097152; base = b - 2048; }
  else if (b < 5120) { src = w2; dst = Wcat + 4194304; base = b - 4096; }
  else if (b < 5248) { src = w3; dst = Wkvb;           base = b - 5120; }
  else if (b < 5376) { src = w4; dst = Wkvb + 131072;  base = b - 5248; }
  else if (b < 5632) { src = w5; dst = Wkvb + 262144;  base = b - 5376; }
  else               { src = w6; dst = Wob;            base = b - 5632; }
  int i = base * 1024 + threadIdx.x * 4;
  float4 v = *(const float4*)(src + i);
  short4 o;
  o.x = f2bs(v.x); o.y = f2bs(v.y); o.z = f2bs(v.z); o.w = f2bs(v.w);
  *(short4*)(dst + i) = o;
}

// ---------------------------------------------------------------------------
// RMS over 512-wide rows, fp32 in -> bf16 out (one wave per row)
// ---------------------------------------------------------------------------
__global__ __launch_bounds__(TPB) void rms512b(
    const float* __restrict__ src, short* __restrict__ dst,
    const float* __restrict__ g, int nrows)
{
  int row = blockIdx.x * (TPB / 64) + (threadIdx.x >> 6);
  int l = threadIdx.x & 63;
  if (row >= nrows) return;
  const float* p = src + (size_t)row * 512;
  float x[8];
  float ss = 0.f;
#pragma unroll
  for (int i = 0; i < 8; ++i) { x[i] = p[i * 64 + l]; ss += x[i] * x[i]; }
#pragma unroll
  for (int msk = 1; msk < 64; msk <<= 1) ss += __shfl_xor(ss, msk);
  float r = rsqrtf(ss * (1.0f / 512.0f) + 1e-6f);
#pragma unroll
  for (int i = 0; i < 8; ++i)
    dst[(size_t)row * 512 + i * 64 + l] = f2bs(x[i] * r * g[i * 64 + l]);
}

// ---------------------------------------------------------------------------
// Fused MFMA GEMM: acc = A[M,K](bf16) @ W[N,K](bf16)^T, 128x128 tile, BK=64,
// double-buffered global_load_lds staging with COUNTED vmcnt (T4):
//   lgkmcnt(0); s_barrier; stage(next); vmcnt(8); compute(cur)
// MODE 0: C fp32 [m*ldc + gn]                                  (W_o GEMM)
// MODE 1: qkv projection: gn<1024 RMS->qb nope | 1024..2047 RMS+rope->qb rope
//         | >=2048 raw fp32 ckv_f                              (x GEMM)
// MODE 2: kv: gn<256 ->kb nope | 256..511 rope->kb | >=512 ->vt transposed
// ---------------------------------------------------------------------------
template <int MODE>
__global__ __launch_bounds__(TPB) void gemm_fused(
    const short* __restrict__ A, const short* __restrict__ W,
    float* __restrict__ Cf, short* __restrict__ qk_out, short* __restrict__ vt,
    float* __restrict__ ckv_f,
    const float* __restrict__ cosb, const float* __restrict__ sinb,
    const float* __restrict__ g_qnope, const float* __restrict__ g_qrope,
    int M, int N, int K, int ldc)
{
  __shared__ short As[2][128 * 64];
  __shared__ short Bs[2][128 * 64];
  const int t = threadIdx.x;
  const int lane = t & 63, wave = t >> 6;
  const int wr = wave >> 1, wc = wave & 1;
  const int li = lane & 15, lh = lane >> 4;
  const int bm = blockIdx.y * 128, bn = blockIdx.x * 128;

  f32x4 acc[4][4];
#pragma unroll
  for (int m = 0; m < 4; ++m)
#pragma unroll
    for (int n = 0; n < 4; ++n) acc[m][n] = (f32x4){0.f, 0.f, 0.f, 0.f};

#define GSTAGE(buf, k0)                                                        \
  {                                                                            \
    _Pragma("unroll") for (int i = 0; i < 4; ++i) {                            \
      int id = i * 256 + t;                                                    \
      int r = id >> 3, cl = id & 7;                                            \
      gll16(A + (size_t)(bm + r) * K + (k0) + ((cl ^ (r & 7)) << 3),           \
            &As[buf][id * 8]);                                                 \
    }                                                                          \
    _Pragma("unroll") for (int i = 0; i < 4; ++i) {                            \
      int id = i * 256 + t;                                                    \
      int r = id >> 3, cl = id & 7;                                            \
      gll16(W + (size_t)(bn + r) * K + (k0) + ((cl ^ (r & 7)) << 3),           \
            &Bs[buf][id * 8]);                                                 \
    }                                                                          \
  }

  GSTAGE(0, 0);
  int cur = 0;
  for (int k0 = 0; k0 < K; k0 += 64) {
    // all waves done reading buf[cur^1] (prev iter); safe to overwrite it
    __builtin_amdgcn_sched_barrier(0);
    asm volatile("s_waitcnt lgkmcnt(0)" ::: "memory");
    __builtin_amdgcn_s_barrier();
    __builtin_amdgcn_sched_barrier(0);
    if (k0 + 64 < K) {
      GSTAGE(cur ^ 1, k0 + 64);
      asm volatile("s_waitcnt vmcnt(8)" ::: "memory");  // cur's 8 loads landed
    } else {
      asm volatile("s_waitcnt vmcnt(0)" ::: "memory");
    }
    __builtin_amdgcn_sched_barrier(0);
    bf16x8 af[2][4], bf[2][4];
#pragma unroll
    for (int m = 0; m < 4; ++m) {
      int r = wr * 64 + m * 16 + li;
#pragma unroll
      for (int kd = 0; kd < 2; ++kd)
        af[kd][m] = *(const bf16x8*)&As[cur][r * 64 + (((kd * 4 + lh) ^ (r & 7)) << 3)];
    }
#pragma unroll
    for (int n = 0; n < 4; ++n) {
      int r = wc * 64 + n * 16 + li;
#pragma unroll
      for (int kd = 0; kd < 2; ++kd)
        bf[kd][n] = *(const bf16x8*)&Bs[cur][r * 64 + (((kd * 4 + lh) ^ (r & 7)) << 3)];
    }
    __builtin_amdgcn_s_setprio(1);
#pragma unroll
    for (int kd = 0; kd < 2; ++kd)
#pragma unroll
      for (int m = 0; m < 4; ++m)
#pragma unroll
        for (int n = 0; n < 4; ++n)
          acc[m][n] = __builtin_amdgcn_mfma_f32_16x16x32_bf16(af[kd][m], bf[kd][n],
                                                              acc[m][n], 0, 0, 0);
    __builtin_amdgcn_s_setprio(0);
    __builtin_amdgcn_sched_barrier(0);
    cur ^= 1;
  }
#undef GSTAGE

  const int colbase = bn + wc * 64;  // wave-uniform, 64-aligned

  if (MODE == 0) {
#pragma unroll
    for (int m = 0; m < 4; ++m) {
      int gm = bm + wr * 64 + m * 16 + lh * 4;
#pragma unroll
      for (int n = 0; n < 4; ++n) {
        int gn = colbase + n * 16 + li;
#pragma unroll
        for (int j = 0; j < 4; ++j)
          Cf[(size_t)(gm + j) * ldc + gn] = acc[m][n][j];
      }
    }
  }

  if (MODE == 1) {
    if (colbase < 2048) {
      const bool isrope = colbase >= 1024;
      const int head = (colbase & 1023) >> 6;
      const float* g = isrope ? g_qrope : g_qnope;
      float gv[4];
#pragma unroll
      for (int nf = 0; nf < 4; ++nf) gv[nf] = g[nf * 16 + li];
#pragma unroll
      for (int m = 0; m < 4; ++m) {
#pragma unroll
        for (int j = 0; j < 4; ++j) {
          int s = bm + wr * 64 + m * 16 + lh * 4 + j;
          float sum = acc[m][0][j] * acc[m][0][j] + acc[m][1][j] * acc[m][1][j] +
                      acc[m][2][j] * acc[m][2][j] + acc[m][3][j] * acc[m][3][j];
          sum += __shfl_xor(sum, 1); sum += __shfl_xor(sum, 2);
          sum += __shfl_xor(sum, 4); sum += __shfl_xor(sum, 8);
          float r = rsqrtf(sum * (1.0f / 64.0f) + 1e-6f);
          float y[4];
#pragma unroll
          for (int nf = 0; nf < 4; ++nf) y[nf] = acc[m][nf][j] * r * gv[nf];
          if (isrope) {
            float yr[4];
#pragma unroll
            for (int nf = 0; nf < 4; ++nf) {
              int c = nf * 16 + li;
              float cs = cosb[s * 64 + c], sn = sinb[s * 64 + c];
              float par = (nf < 2) ? -y[nf + 2] : y[nf - 2];
              yr[nf] = y[nf] * cs + par * sn;
            }
#pragma unroll
            for (int nf = 0; nf < 4; ++nf) y[nf] = yr[nf];
          }
#pragma unroll
          for (int nf = 0; nf < 4; ++nf)
            qk_out[(size_t)s * 2048 + head * 128 + (isrope ? 64 : 0) + nf * 16 + li] =
                f2bs(y[nf]);
        }
      }
    } else {
      const int c0 = colbase - 2048;
#pragma unroll
      for (int m = 0; m < 4; ++m) {
        int gm = bm + wr * 64 + m * 16 + lh * 4;
#pragma unroll
        for (int n = 0; n < 4; ++n) {
          int c = c0 + n * 16 + li;
#pragma unroll
          for (int j = 0; j < 4; ++j)
            ckv_f[(size_t)(gm + j) * 512 + c] = acc[m][n][j];
        }
      }
    }
  }

  if (MODE == 2) {
    if (colbase < 512) {
      const bool isrope = colbase >= 256;
      const int kvh = (colbase & 255) >> 6;
#pragma unroll
      for (int m = 0; m < 4; ++m) {
#pragma unroll
        for (int j = 0; j < 4; ++j) {
          int s = bm + wr * 64 + m * 16 + lh * 4 + j;
          float y[4];
#pragma unroll
          for (int nf = 0; nf < 4; ++nf) y[nf] = acc[m][nf][j];
          if (isrope) {
            float yr[4];
#pragma unroll
            for (int nf = 0; nf < 4; ++nf) {
              int c = nf * 16 + li;
              float cs = cosb[s * 64 + c], sn = sinb[s * 64 + c];
              float par = (nf < 2) ? -y[nf + 2] : y[nf - 2];
              yr[nf] = y[nf] * cs + par * sn;
            }
#pragma unroll
            for (int nf = 0; nf < 4; ++nf) y[nf] = yr[nf];
          }
#pragma unroll
          for (int nf = 0; nf < 4; ++nf)
            qk_out[(size_t)s * 512 + kvh * 128 + (isrope ? 64 : 0) + nf * 16 + li] =
                f2bs(y[nf]);
        }
      }
    } else {
#pragma unroll
      for (int m = 0; m < 4; ++m) {
        int s0 = bm + wr * 64 + m * 16 + lh * 4;
#pragma unroll
        for (int nf = 0; nf < 4; ++nf) {
          int d = colbase - 512 + nf * 16 + li;
          int kvh = d >> 7, dd = d & 127;
          short4 pk;
          pk.x = f2bs(acc[m][nf][0]); pk.y = f2bs(acc[m][nf][1]);
          pk.z = f2bs(acc[m][nf][2]); pk.w = f2bs(acc[m][nf][3]);
          *(short4*)&vt[(size_t)kvh * 262144 + (size_t)dd * 2048 + s0] = pk;
        }
      }
    }
  }
}

// ---------------------------------------------------------------------------
// MFMA flash attention, causal. Double-buffered K/V staging with counted
// vmcnt (same pattern as GEMM). Block = 4 waves, BQ=64 (16 q-rows/wave),
// BK=64, HD=128. setprio around MFMA clusters; rescale skipped when c==1.
// qb [S][16*128], kb [S][4*128], vt [4][128][S], ob bf16 [S][16*128]
// ---------------------------------------------------------------------------
__global__ __launch_bounds__(TPB) void attn_mfma(
    const short* __restrict__ qb, const short* __restrict__ kb,
    const short* __restrict__ vt, short* __restrict__ ob)
{
  __shared__ short Ks[2][64 * 128];   // [kpos][d] swizzled
  __shared__ short Vs[2][128 * 64];   // [d][kpos] swizzled
  __shared__ short Ps[4][16 * 64];    // per-wave [q][kpos] swizzled
  const int h = blockIdx.x;
  const int qt = gridDim.y - 1 - blockIdx.y;  // longest blocks first
  const int kvh = h >> 2;
  const int t = threadIdx.x, lane = t & 63, wave = t >> 6;
  const int li = lane & 15, lh = lane >> 4;
  const int q0 = qt * 64, q0w = q0 + wave * 16;
  const float scale = 0.08838834764831845f;  // 1/sqrt(128)

  bf16x8 qf[4];
#pragma unroll
  for (int kd = 0; kd < 4; ++kd)
    qf[kd] = *(const bf16x8*)(qb + (size_t)(q0w + li) * 2048 + h * 128 + kd * 32 + lh * 8);

  f32x4 o[8];
#pragma unroll
  for (int n = 0; n < 8; ++n) o[n] = (f32x4){0.f, 0.f, 0.f, 0.f};
  float m_i[4] = {-1e30f, -1e30f, -1e30f, -1e30f};
  float l_i[4] = {0.f, 0.f, 0.f, 0.f};

#define ASTAGE(buf, kbase)                                                     \
  {                                                                            \
    _Pragma("unroll") for (int i = 0; i < 4; ++i) {                            \
      int c = t + i * 256;                                                     \
      int kpos = c >> 4, dcl = (c & 15) ^ (kpos & 7);                          \
      gll16(kb + (size_t)((kbase) + kpos) * 512 + kvh * 128 + dcl * 8,         \
            &Ks[buf][c * 8]);                                                  \
    }                                                                          \
    _Pragma("unroll") for (int i = 0; i < 4; ++i) {                            \
      int c = t + i * 256;                                                     \
      int d = c >> 3, kpl = (c & 7) ^ (d & 7);                                 \
      gll16(vt + (size_t)kvh * 262144 + (size_t)d * 2048 + (kbase) + kpl * 8,  \
            &Vs[buf][c * 8]);                                                  \
    }                                                                          \
  }

  short* pw = Ps[wave];
  const int nkt = qt + 1;
  ASTAGE(0, 0);
  int cur = 0;
  for (int kt = 0; kt < nkt; ++kt) {
    const int kbase = kt * 64;
    __builtin_amdgcn_sched_barrier(0);
    asm volatile("s_waitcnt lgkmcnt(0)" ::: "memory");
    __builtin_amdgcn_s_barrier();
    __builtin_amdgcn_sched_barrier(0);
    if (kt + 1 < nkt) {
      ASTAGE(cur ^ 1, kbase + 64);
      asm volatile("s_waitcnt vmcnt(8)" ::: "memory");  // cur's 8 loads landed
    } else {
      asm volatile("s_waitcnt vmcnt(0)" ::: "memory");
    }
    __builtin_amdgcn_sched_barrier(0);

    // ---- S = Q K^T ----
    f32x4 s[4];
#pragma unroll
    for (int n = 0; n < 4; ++n) s[n] = (f32x4){0.f, 0.f, 0.f, 0.f};
    __builtin_amdgcn_s_setprio(1);
#pragma unroll
    for (int n = 0; n < 4; ++n) {
      int kpos = n * 16 + li;
#pragma unroll
      for (int kd = 0; kd < 4; ++kd) {
        int cph = (kd * 4 + lh) ^ (kpos & 7);
        bf16x8 kf = *(const bf16x8*)&Ks[cur][kpos * 128 + cph * 8];
        s[n] = __builtin_amdgcn_mfma_f32_16x16x32_bf16(qf[kd], kf, s[n], 0, 0, 0);
      }
    }
    __builtin_amdgcn_s_setprio(0);
    // ---- scale + causal mask ----
    float sv[4][4];
    const bool diag = (kt == nkt - 1);
#pragma unroll
    for (int n = 0; n < 4; ++n)
#pragma unroll
      for (int j = 0; j < 4; ++j) {
        float val = s[n][j] * scale;
        if (diag) {
          int kg = kbase + n * 16 + li;
          int qg = q0w + lh * 4 + j;
          if (kg > qg) val = -1e30f;
        }
        sv[n][j] = val;
      }
    // ---- online softmax ----
    float c_[4];
#pragma unroll
    for (int j = 0; j < 4; ++j) {
      float rm = fmaxf(fmaxf(sv[0][j], sv[1][j]), fmaxf(sv[2][j], sv[3][j]));
      rm = fmaxf(rm, __shfl_xor(rm, 1));
      rm = fmaxf(rm, __shfl_xor(rm, 2));
      rm = fmaxf(rm, __shfl_xor(rm, 4));
      rm = fmaxf(rm, __shfl_xor(rm, 8));
      float mn = fmaxf(m_i[j], rm);
      c_[j] = __expf(m_i[j] - mn);
      m_i[j] = mn;
    }
#pragma unroll
    for (int n = 0; n < 4; ++n)
#pragma unroll
      for (int j = 0; j < 4; ++j) sv[n][j] = __expf(sv[n][j] - m_i[j]);
#pragma unroll
    for (int j = 0; j < 4; ++j) {
      float rs = sv[0][j] + sv[1][j] + sv[2][j] + sv[3][j];
      rs += __shfl_xor(rs, 1);
      rs += __shfl_xor(rs, 2);
      rs += __shfl_xor(rs, 4);
      rs += __shfl_xor(rs, 8);
      l_i[j] = l_i[j] * c_[j] + rs;
    }
    // ---- P -> LDS (bf16, swizzled; per-wave buffer) ----
#pragma unroll
    for (int n = 0; n < 4; ++n)
#pragma unroll
      for (int j = 0; j < 4; ++j) {
        int qq = lh * 4 + j, kp = n * 16 + li;
        pw[qq * 64 + (kp ^ ((qq & 7) << 3))] = f2bs(sv[n][j]);
      }
    // ---- rescale O (skip when all c == 1) ----
    if (__any((c_[0] < 1.f) | (c_[1] < 1.f) | (c_[2] < 1.f) | (c_[3] < 1.f))) {
#pragma unroll
      for (int n = 0; n < 8; ++n)
#pragma unroll
        for (int j = 0; j < 4; ++j) o[n][j] *= c_[j];
    }
    // same-wave LDS write->read fence (rule #18)
    asm volatile("s_waitcnt lgkmcnt(0)" ::: "memory");
    __builtin_amdgcn_sched_barrier(0);
    // ---- O += P V ----
    __builtin_amdgcn_s_setprio(1);
#pragma unroll
    for (int kk = 0; kk < 2; ++kk) {
      int kp0 = kk * 32 + lh * 8;
      bf16x8 pf = *(const bf16x8*)&pw[li * 64 + (kp0 ^ ((li & 7) << 3))];
#pragma unroll
      for (int n = 0; n < 8; ++n) {
        int d = n * 16 + li;
        bf16x8 vf = *(const bf16x8*)&Vs[cur][d * 64 + (kp0 ^ ((d & 7) << 3))];
        o[n] = __builtin_amdgcn_mfma_f32_16x16x32_bf16(pf, vf, o[n], 0, 0, 0);
      }
    }
    __builtin_amdgcn_s_setprio(0);
    __builtin_amdgcn_sched_barrier(0);
    cur ^= 1;
  }
#undef ASTAGE
  float inv[4];
#pragma unroll
  for (int j = 0; j < 4; ++j) inv[j] = 1.0f / l_i[j];
#pragma unroll
  for (int n = 0; n < 8; ++n)
#pragma unroll
    for (int j = 0; j < 4; ++j)
      ob[(size_t)(q0w + lh * 4 + j) * 2048 + h * 128 + n * 16 + li] =
          f2bs(o[n][j] * inv[j]);
}

// ---------------------------------------------------------------------------
extern "C" void kernel_launch(void* const* d_in, const int* in_sizes, int n_in,
                              void* d_out, int out_size, void* d_ws, size_t ws_size,
                              hipStream_t stream) {
  const float* x         = (const float*)d_in[0];
  const float* cosb      = (const float*)d_in[1];
  const float* sinb      = (const float*)d_in[2];
  const float* Wq_nope   = (const float*)d_in[3];
  const float* Wq_rope   = (const float*)d_in[4];
  const float* g_qnope   = (const float*)d_in[5];
  const float* g_qrope   = (const float*)d_in[6];
  const float* W_kv_down = (const float*)d_in[7];
  const float* g_ckv     = (const float*)d_in[8];
  const float* W_k_nope  = (const float*)d_in[9];
  const float* W_k_rope  = (const float*)d_in[10];
  const float* W_v       = (const float*)d_in[11];
  const float* W_o       = (const float*)d_in[12];
  float* out = (float*)d_out;

  float* ws = (float*)d_ws;
  float* ckv_f = ws;                         // 1,048,576 floats
  short* sb   = (short*)(ws + 1048576);
  short* xb   = sb;                          // 4,194,304 (reused as aob)
  short* Wcat = sb + 4194304;                // 5,242,880  [2560][2048]
  short* Wkvb = Wcat + 5242880;              //   524,288  [1024][512]
  short* Wob  = Wkvb + 524288;               // 4,194,304
  short* qb   = Wob + 4194304;               // 4,194,304
  short* ckvb = qb + 4194304;                // 1,048,576
  short* kb   = ckvb + 1048576;              // 1,048,576
  short* vt   = kb + 1048576;                // 1,048,576
  short* aob  = xb;

  dim3 blk(TPB);

  cvt_f2b<<<4096, blk, 0, stream>>>(x, xb, 4194304);
  cvt_weights<<<9728, blk, 0, stream>>>(Wq_nope, Wq_rope, W_kv_down, W_k_nope,
                                        W_k_rope, W_v, W_o, Wcat, Wkvb, Wob);

  // x @ [Wq_nope; Wq_rope; W_kv_down]^T  (N=2560, K=2048) fused RMS/rope -> qb, ckv_f
  gemm_fused<1><<<dim3(20, 16), blk, 0, stream>>>(
      xb, Wcat, nullptr, qb, nullptr, ckv_f, cosb, sinb, g_qnope, g_qrope,
      2048, 2560, 2048, 0);

  rms512b<<<512, blk, 0, stream>>>(ckv_f, ckvb, g_ckv, 2048);

  // ckv @ [W_k_nope; W_k_rope; W_v]^T (N=1024, K=512) fused rope/transpose -> kb, vt
  gemm_fused<2><<<dim3(8, 16), blk, 0, stream>>>(
      ckvb, Wkvb, nullptr, kb, vt, nullptr, cosb, sinb, nullptr, nullptr,
      2048, 1024, 512, 0);

  attn_mfma<<<dim3(16, 32), blk, 0, stream>>>(qb, kb, vt, aob);

  // out = ao @ W_o^T (N=2048, K=2048)
  gemm_fused<0><<<dim3(16, 16), blk, 0, stream>>>(
      aob, Wob, out, nullptr, nullptr, nullptr, nullptr, nullptr, nullptr, nullptr,
      2048, 2048, 2048, 2048);
}